// Round 10
// baseline (105.148 us; speedup 1.0000x reference)
//
#include <hip/hip_runtime.h>
#include <math.h>

typedef __attribute__((ext_vector_type(8))) short short8;  // 8 bf16 = 4 VGPRs
typedef __attribute__((ext_vector_type(4))) float f32x4;

// Problem dims
#define D0n 8
#define D1n 12
#define D2n 6
#define Ln 2000
#define An 21
#define KPn 8
#define Un 48
#define PPn 1993              // L - k + 1
#define Bn 576                // D0*D1*D2
#define S_SIZE 4608           // (D0*D1) * U
#define R_SIZE 8064

// Conv tiling: 512 threads = 8 waves; wave = 32 positions x 48 u.
// Block: 2 tiles of 256 positions; grid (4, 576) = 2304 blocks = 9/CU.
#define BPn 256
#define NBX 4
#define XROWS 264              // 256 + halo
#define XBUF_BYTES (XROWS * 64)  // 16896
#define RB_BYTES (384 * 64)    // 24576
#define BOFF (2 * XBUF_BYTES)
#define RED_OFF (BOFF + RB_BYTES)

// X' in ws: bf16, padded 21->32 (64B rows), pre-swizzled. Offset 32KB.
#define XP_OFF 32768
#define XP_BYTES ((size_t)Bn * Ln * 64)   // 73,728,000
#define WS_NEED (XP_OFF + XP_BYTES)

// XOR swizzle within each 512B (8-row) group; bijective, 16B-granular.
__device__ __forceinline__ int swz(int b) { return b ^ ((b >> 2) & 0x70); }

__device__ __forceinline__ unsigned int fkey(float f) {
    unsigned int u = __float_as_uint(f);
    return (u & 0x80000000u) ? ~u : (u | 0x80000000u);
}
__device__ __forceinline__ float funkey(unsigned int k) {
    return __uint_as_float((k & 0x80000000u) ? (k ^ 0x80000000u) : ~k);
}
__device__ __forceinline__ unsigned short f2bf(float v) {
    unsigned int b = __float_as_uint(v);
    return (unsigned short)((b + 0x7FFFu + ((b >> 16) & 1u)) >> 16);  // RNE
}

#define GLOAD_LDS16(g, l)                                                     \
    __builtin_amdgcn_global_load_lds(                                          \
        (const __attribute__((address_space(1))) void*)(g),                    \
        (__attribute__((address_space(3))) void*)(l), 16, 0, 0)

// lgkm-only wait + raw barrier (fallback path).
#define TILE_BARRIER()                                                        \
    do {                                                                      \
        asm volatile("s_waitcnt lgkmcnt(0)" ::: "memory");                    \
        __builtin_amdgcn_s_barrier();                                         \
        asm volatile("" ::: "memory");                                        \
    } while (0)

// Kernel 1: zero S-keys; R = log(max(softmax(P_logit)/Q, eps)) -> fp32 to
// d_out + bf16 padded pre-swizzled copy to ws[0:24576).
__global__ void k_profile(const float* __restrict__ P_logit,
                          const float* __restrict__ Q,
                          float* __restrict__ Rout,
                          unsigned short* __restrict__ Rb,
                          unsigned int* __restrict__ Skey) {
    int t = blockIdx.x * blockDim.x + threadIdx.x;
    if (t < S_SIZE) Skey[t] = 0u;
    if (t >= KPn * Un) return;
    int kp = t / Un, u = t % Un;
    const float* pl = P_logit + kp * (An * Un) + u;
    float v[An];
    float m = -INFINITY;
#pragma unroll
    for (int a = 0; a < An; ++a) { v[a] = pl[a * Un]; m = fmaxf(m, v[a]); }
    float s = 0.f;
#pragma unroll
    for (int a = 0; a < An; ++a) { v[a] = expf(v[a] - m); s += v[a]; }
    float inv = 1.f / s;
    int rowp = kp * Un + u;
#pragma unroll
    for (int a = 0; a < An; ++a) {
        float r = logf(fmaxf(v[a] * inv / Q[a], 1e-6f));
        Rout[(kp * An + a) * Un + u] = r;
        Rb[swz(rowp * 64 + a * 2) >> 1] = f2bf(r);
    }
#pragma unroll
    for (int a = An; a < 32; ++a) Rb[swz(rowp * 64 + a * 2) >> 1] = 0;
}

// Kernel 1b: X' = bf16(X), rows padded to 32 elems, swizzled. One thread per
// 16B dest slot (4 per row). Exact grid: Bn*Ln*4 / 256 = 18000 blocks.
__global__ __launch_bounds__(256) void k_xconv(const float* __restrict__ X,
                                               unsigned short* __restrict__ Xp) {
    int s = blockIdx.x * 256 + threadIdx.x;
    int R = s >> 2, part = s & 3;
    unsigned int pk[4];
    if (part == 3) {
        pk[0] = pk[1] = pk[2] = pk[3] = 0u;   // pure pad slot
    } else {
        const float* src = X + (size_t)R * An + part * 8;
        int nv = An - part * 8; if (nv > 8) nv = 8;   // 8, 8, 5
        float f[8];
#pragma unroll
        for (int e = 0; e < 8; ++e) f[e] = (e < nv) ? src[e] : 0.f;
#pragma unroll
        for (int i2 = 0; i2 < 4; ++i2)
            pk[i2] = (unsigned int)f2bf(f[2 * i2]) |
                     ((unsigned int)f2bf(f[2 * i2 + 1]) << 16);
    }
    uint4 v = {pk[0], pk[1], pk[2], pk[3]};
    *(uint4*)((char*)Xp + swz(R * 64 + part * 16)) = v;
}

// ---- shared q-loop: A-operand = R rows (u), B-operand = X rows (pos) ----
__device__ __forceinline__ void qloop8(const char* smem, const char* xb,
                                       int lr, int ls, int pw,
                                       f32x4 acc[3][2]) {
#pragma unroll
    for (int q = 0; q < KPn; ++q) {
        const int rr = q * Un + lr;
        short8 rf0 = *(const short8*)(smem + BOFF + swz(rr * 64 + ls * 16));
        short8 rf1 = *(const short8*)(smem + BOFF + swz((rr + 16) * 64 + ls * 16));
        short8 rf2 = *(const short8*)(smem + BOFF + swz((rr + 32) * 64 + ls * 16));
        const int xr = pw + q + lr;
        short8 xf0 = *(const short8*)(xb + swz(xr * 64 + ls * 16));
        short8 xf1 = *(const short8*)(xb + swz((xr + 16) * 64 + ls * 16));
        acc[0][0] = __builtin_amdgcn_mfma_f32_16x16x32_bf16(rf0, xf0, acc[0][0], 0, 0, 0);
        acc[0][1] = __builtin_amdgcn_mfma_f32_16x16x32_bf16(rf0, xf1, acc[0][1], 0, 0, 0);
        acc[1][0] = __builtin_amdgcn_mfma_f32_16x16x32_bf16(rf1, xf0, acc[1][0], 0, 0, 0);
        acc[1][1] = __builtin_amdgcn_mfma_f32_16x16x32_bf16(rf1, xf1, acc[1][1], 0, 0, 0);
        acc[2][0] = __builtin_amdgcn_mfma_f32_16x16x32_bf16(rf2, xf0, acc[2][0], 0, 0, 0);
        acc[2][1] = __builtin_amdgcn_mfma_f32_16x16x32_bf16(rf2, xf1, acc[2][1], 0, 0, 0);
    }
}

// Z stores (nontemporal variant for DMA path).
__device__ __forceinline__ void store_tile_nt(float* __restrict__ Z, int b,
                                              int tp0, int pw, int lr, int ls,
                                              const f32x4 acc[3][2],
                                              float smax[3][4]) {
#pragma unroll
    for (int np = 0; np < 2; ++np) {
        int p = tp0 + pw + np * 16 + lr;
        if (p < PPn) {
            float* zp = Z + ((size_t)b * PPn + p) * Un + ls * 4;
#pragma unroll
            for (int nu = 0; nu < 3; ++nu) {
                __builtin_nontemporal_store(acc[nu][np], (f32x4*)(zp + nu * 16));
#pragma unroll
                for (int r = 0; r < 4; ++r)
                    smax[nu][r] = fmaxf(smax[nu][r], acc[nu][np][r]);
            }
        }
    }
}

__device__ __forceinline__ void store_tile(float* __restrict__ Z, int b,
                                           int tp0, int pw, int lr, int ls,
                                           const f32x4 acc[3][2],
                                           float smax[3][4]) {
#pragma unroll
    for (int np = 0; np < 2; ++np) {
        int p = tp0 + pw + np * 16 + lr;
        if (p < PPn) {
            float* zp = Z + ((size_t)b * PPn + p) * Un + ls * 4;
#pragma unroll
            for (int nu = 0; nu < 3; ++nu) {
                *(f32x4*)(zp + nu * 16) = acc[nu][np];
#pragma unroll
                for (int r = 0; r < 4; ++r)
                    smax[nu][r] = fmaxf(smax[nu][r], acc[nu][np][r]);
            }
        }
    }
}

// Stage one tile of X' into LDS via DMA (masked tail ok: active lanes are a
// prefix of the wave, so wave-uniform-base + lane*16 holds).
__device__ __forceinline__ void xstage(const unsigned short* __restrict__ Xp,
                                       int b, int p0, int t, char* dst) {
    int rows = min(XROWS, Ln - p0);
    int slots = rows * 4;
    const char* src = (const char*)Xp + ((size_t)b * Ln + p0) * 64;
#pragma unroll
    for (int i = 0; i < 3; ++i) {
        int idx = t + i * 512;
        if (idx < slots) GLOAD_LDS16(src + (size_t)idx * 16, dst + idx * 16);
    }
}

// Kernel 2 (DMA path): staging is pure global_load_lds of pre-swizzled X'.
__global__ __launch_bounds__(512) void k_conv(
        const unsigned short* __restrict__ Rb,
        const unsigned short* __restrict__ Xp,
        float* __restrict__ Z,
        unsigned int* __restrict__ Skey) {
    __shared__ char smem[RED_OFF + 8 * Un * 4];
    const int b = blockIdx.y;
    const int base_p = blockIdx.x * (2 * BPn);
    const int t = threadIdx.x;
    const int w = t >> 6;
    const int l = t & 63;
    const int lr = l & 15;
    const int ls = l >> 4;
    const int pw = w * 32;

    // ---- Prologue: stage B + tile0, all DMA ----
    {
        const char* src = (const char*)Rb;
        char* dst = smem + BOFF;
#pragma unroll
        for (int i = 0; i < RB_BYTES / 16 / 512; ++i) {  // 3 full iters
            int idx = t + i * 512;
            GLOAD_LDS16(src + idx * 16, dst + idx * 16);
        }
    }
    xstage(Xp, b, base_p, t, (char*)smem);   // tile0: always 264 rows, full
    __syncthreads();                          // drains all DMA (vmcnt0+lgkm0)

    float smax[3][4];
#pragma unroll
    for (int nu = 0; nu < 3; ++nu)
#pragma unroll
        for (int r = 0; r < 4; ++r) smax[nu][r] = -INFINITY;

    f32x4 acc[3][2];

    // ---- Tile 0 ----
    xstage(Xp, b, base_p + BPn, t, (char*)smem + XBUF_BYTES);  // async prefetch
#pragma unroll
    for (int nu = 0; nu < 3; ++nu)
#pragma unroll
        for (int np = 0; np < 2; ++np) acc[nu][np] = (f32x4){0.f, 0.f, 0.f, 0.f};
    qloop8((const char*)smem, (const char*)smem, lr, ls, pw, acc);
    // Wait the 3 prefetch DMAs (only outstanding VMEM; long done under qloop),
    // then issue Z-stores and cross the barrier with stores still in flight.
    asm volatile("s_waitcnt vmcnt(0)" ::: "memory");
    store_tile_nt(Z, b, base_p, pw, lr, ls, acc, smax);
    __builtin_amdgcn_s_barrier();

    // ---- Tile 1 ----
#pragma unroll
    for (int nu = 0; nu < 3; ++nu)
#pragma unroll
        for (int np = 0; np < 2; ++np) acc[nu][np] = (f32x4){0.f, 0.f, 0.f, 0.f};
    qloop8((const char*)smem, (const char*)smem + XBUF_BYTES, lr, ls, pw, acc);
    store_tile_nt(Z, b, base_p + BPn, pw, lr, ls, acc, smax);

    // ---- S reduction ----
    float* red = (float*)(smem + RED_OFF);
#pragma unroll
    for (int nu = 0; nu < 3; ++nu)
#pragma unroll
        for (int r = 0; r < 4; ++r) {
            float v = smax[nu][r];
            v = fmaxf(v, __shfl_xor(v, 1));
            v = fmaxf(v, __shfl_xor(v, 2));
            v = fmaxf(v, __shfl_xor(v, 4));
            v = fmaxf(v, __shfl_xor(v, 8));
            if (lr == 0) red[w * Un + nu * 16 + ls * 4 + r] = v;
        }
    __syncthreads();
    if (t < Un) {
        float m = -INFINITY;
#pragma unroll
        for (int wv = 0; wv < 8; ++wv) m = fmaxf(m, red[wv * Un + t]);
        atomicMax(&Skey[(b / D2n) * Un + t], fkey(m));
    }
}

// ================= Fallback path (exact R8 structure) =================
__device__ __forceinline__ void xwrite4(char* xbase, int idx, f32x4 g) {
    int fi = idx * 4;
    int row = fi / An;
    int a = fi - row * An;
#pragma unroll
    for (int e = 0; e < 4; ++e) {
        *(unsigned short*)(xbase + swz(row * 64 + a * 2)) = f2bf(g[e]);
        ++a;
        if (a == An) { a = 0; ++row; }
    }
}

__device__ __forceinline__ void xload(const float* __restrict__ X, int b,
                                      int tp0, int t, f32x4 g[3], int& n4) {
    int rows = min(XROWS, Ln - tp0);
    n4 = rows * An / 4;
    const f32x4* src = (const f32x4*)(X + ((size_t)b * Ln + tp0) * An);
#pragma unroll
    for (int i = 0; i < 3; ++i) {
        int idx = t + i * 512;
        g[i] = (idx < n4) ? src[idx] : (f32x4){0.f, 0.f, 0.f, 0.f};
    }
}

__device__ __forceinline__ void xstore(char* xbase, int t, const f32x4 g[3],
                                       int n4) {
#pragma unroll
    for (int i = 0; i < 3; ++i) {
        int idx = t + i * 512;
        if (idx < n4) xwrite4(xbase, idx, g[i]);
    }
}

__global__ __launch_bounds__(512, 4) void k_conv_fb(
        const float* __restrict__ X,
        const unsigned short* __restrict__ Rb,
        float* __restrict__ Z,
        unsigned int* __restrict__ Skey) {
    __shared__ char smem[RED_OFF + 8 * Un * 4];
    const int b = blockIdx.y;
    const int base_p = blockIdx.x * (2 * BPn);
    const int t = threadIdx.x;
    const int w = t >> 6;
    const int l = t & 63;
    const int lr = l & 15;
    const int ls = l >> 4;
    const int pw = w * 32;

    {
        const char* src = (const char*)Rb;
        char* dst = smem + BOFF;
#pragma unroll
        for (int i = 0; i < RB_BYTES / 16 / 512; ++i) {
            int idx = t + i * 512;
            GLOAD_LDS16(src + idx * 16, dst + idx * 16);
        }
    }
    {
        uint4 z4 = {0u, 0u, 0u, 0u};
        uint4* xs = (uint4*)smem;
        for (int i = t; i < 2 * XBUF_BYTES / 16; i += 512) xs[i] = z4;
    }
    f32x4 g[3];
    int n4;
    xload(X, b, base_p, t, g, n4);
    __syncthreads();
    xstore((char*)smem, t, g, n4);
    TILE_BARRIER();

    float smax[3][4];
#pragma unroll
    for (int nu = 0; nu < 3; ++nu)
#pragma unroll
        for (int r = 0; r < 4; ++r) smax[nu][r] = -INFINITY;

    f32x4 acc[3][2];

    xload(X, b, base_p + BPn, t, g, n4);
#pragma unroll
    for (int nu = 0; nu < 3; ++nu)
#pragma unroll
        for (int np = 0; np < 2; ++np) acc[nu][np] = (f32x4){0.f, 0.f, 0.f, 0.f};
    qloop8((const char*)smem, (const char*)smem, lr, ls, pw, acc);
    xstore((char*)smem + XBUF_BYTES, t, g, n4);
    store_tile(Z, b, base_p, pw, lr, ls, acc, smax);
    TILE_BARRIER();

#pragma unroll
    for (int nu = 0; nu < 3; ++nu)
#pragma unroll
        for (int np = 0; np < 2; ++np) acc[nu][np] = (f32x4){0.f, 0.f, 0.f, 0.f};
    qloop8((const char*)smem, (const char*)smem + XBUF_BYTES, lr, ls, pw, acc);
    store_tile(Z, b, base_p + BPn, pw, lr, ls, acc, smax);

    float* red = (float*)(smem + RED_OFF);
#pragma unroll
    for (int nu = 0; nu < 3; ++nu)
#pragma unroll
        for (int r = 0; r < 4; ++r) {
            float v = smax[nu][r];
            v = fmaxf(v, __shfl_xor(v, 1));
            v = fmaxf(v, __shfl_xor(v, 2));
            v = fmaxf(v, __shfl_xor(v, 4));
            v = fmaxf(v, __shfl_xor(v, 8));
            if (lr == 0) red[w * Un + nu * 16 + ls * 4 + r] = v;
        }
    __syncthreads();
    if (t < Un) {
        float m = -INFINITY;
#pragma unroll
        for (int wv = 0; wv < 8; ++wv) m = fmaxf(m, red[wv * Un + t]);
        atomicMax(&Skey[(b / D2n) * Un + t], fkey(m));
    }
}

// Kernel 3: decode monotone keys -> float S, in place.
__global__ void k_decode(unsigned int* __restrict__ Skey) {
    int t = blockIdx.x * blockDim.x + threadIdx.x;
    if (t < S_SIZE) {
        float f = funkey(Skey[t]);
        ((float*)Skey)[t] = f;
    }
}

extern "C" void kernel_launch(void* const* d_in, const int* in_sizes, int n_in,
                              void* d_out, int out_size, void* d_ws, size_t ws_size,
                              hipStream_t stream) {
    const float* X = (const float*)d_in[0];
    const float* P_logit = (const float*)d_in[1];
    const float* Q = (const float*)d_in[2];

    float* S = (float*)d_out;
    float* Rout = S + S_SIZE;
    float* Z = Rout + R_SIZE;
    unsigned short* Rb = (unsigned short*)d_ws;

    k_profile<<<(S_SIZE + 63) / 64, 64, 0, stream>>>(P_logit, Q, Rout, Rb,
                                                     (unsigned int*)d_out);

    dim3 grid(NBX, Bn);
    if (ws_size >= WS_NEED) {
        unsigned short* Xp = (unsigned short*)((char*)d_ws + XP_OFF);
        k_xconv<<<(Bn * Ln * 4) / 256, 256, 0, stream>>>(X, Xp);
        k_conv<<<grid, 512, 0, stream>>>(Rb, Xp, Z, (unsigned int*)d_out);
    } else {
        k_conv_fb<<<grid, 512, 0, stream>>>(X, Rb, Z, (unsigned int*)d_out);
    }

    k_decode<<<(S_SIZE + 255) / 256, 256, 0, stream>>>((unsigned int*)d_out);
}